// Round 1
// baseline (1232.660 us; speedup 1.0000x reference)
//
#include <hip/hip_runtime.h>

#define LCONV 4096
#define NFFT 8192
#define NT 256
#define HCH 1024
#define BATCH 16
#define PI_F 3.14159265358979f

// Radix-2 DIF: natural input order -> bit-reversed output order.
__device__ __forceinline__ void fft_dif(float* re, float* im, int tid) {
    for (int half = NFFT / 2; half >= 1; half >>= 1) {
        float inv_half = 1.0f / (float)half;
        __syncthreads();
        for (int w = tid; w < NFFT / 2; w += NT) {
            int j = w & (half - 1);
            int base = ((w & ~(half - 1)) << 1) | j;
            float ur = re[base], ui = im[base];
            float vr = re[base + half], vi = im[base + half];
            re[base] = ur + vr;
            im[base] = ui + vi;
            float dr = ur - vr, di = ui - vi;
            float ang = -PI_F * ((float)j * inv_half);
            float s, c;
            __sincosf(ang, &s, &c);
            re[base + half] = dr * c - di * s;
            im[base + half] = dr * s + di * c;
        }
    }
    __syncthreads();
}

// Radix-2 DIT inverse (conjugate twiddles): bit-reversed input -> natural output.
// No 1/N scaling here (folded into the pointwise multiply).
__device__ __forceinline__ void fft_dit_inv(float* re, float* im, int tid) {
    for (int half = 1; half <= NFFT / 2; half <<= 1) {
        float inv_half = 1.0f / (float)half;
        __syncthreads();
        for (int w = tid; w < NFFT / 2; w += NT) {
            int j = w & (half - 1);
            int base = ((w & ~(half - 1)) << 1) | j;
            float ang = PI_F * ((float)j * inv_half);
            float s, c;
            __sincosf(ang, &s, &c);
            float tr = re[base + half], ti = im[base + half];
            float vr = tr * c - ti * s;
            float vi = tr * s + ti * c;
            float ur = re[base], ui = im[base];
            re[base] = ur + vr;
            im[base] = ui + vi;
            re[base + half] = ur - vr;
            im[base + half] = ui - vi;
        }
    }
    __syncthreads();
}

// Kernel 1: Kf[h] = DIF-FFT(pad(k[h], 8192)), stored bit-reversed, fp32 complex.
__global__ __launch_bounds__(NT) void kfft_kernel(const float* __restrict__ k,
                                                  float2* __restrict__ Kf) {
    __shared__ float re[NFFT];
    __shared__ float im[NFFT];
    int h = blockIdx.x;
    int tid = threadIdx.x;
    const float* krow = k + (size_t)h * LCONV;
#pragma unroll
    for (int j = 0; j < LCONV / NT; ++j) {
        int i = tid + j * NT;
        re[i] = krow[i];
        im[i] = 0.0f;
        re[i + LCONV] = 0.0f;
        im[i + LCONV] = 0.0f;
    }
    fft_dif(re, im, tid);
    float2* out = Kf + (size_t)h * NFFT;
    for (int i = tid; i < NFFT; i += NT)
        out[i] = make_float2(re[i], im[i]);
}

// Kernel 2: per (h, batch-pair): z = x[b0] + i*x[b1]  ->  DIF FFT  ->
// pointwise * Kf[h] * (1/N)  ->  DIT inverse  ->  y[b0]=Re+x*D, y[b1]=Im+x*D.
__global__ __launch_bounds__(NT) void conv_kernel(const float* __restrict__ x,
                                                  const float2* __restrict__ Kf,
                                                  const float* __restrict__ Dv,
                                                  float* __restrict__ y) {
    __shared__ float re[NFFT];
    __shared__ float im[NFFT];
    int bid = blockIdx.x;
    int h = bid >> 3;          // 8 consecutive blocks share one h (L2 reuse of Kf)
    int pb = bid & 7;
    int b0 = pb * 2, b1 = pb * 2 + 1;
    int tid = threadIdx.x;

    const float* x0 = x + ((size_t)b0 * HCH + h) * LCONV;
    const float* x1 = x + ((size_t)b1 * HCH + h) * LCONV;

    float xr0[16], xr1[16];
#pragma unroll
    for (int j = 0; j < 16; ++j) {
        int i = tid + j * NT;
        float a = x0[i];
        float b = x1[i];
        xr0[j] = a;
        xr1[j] = b;
        re[i] = a;
        im[i] = b;
        re[i + LCONV] = 0.0f;
        im[i + LCONV] = 0.0f;
    }

    fft_dif(re, im, tid);

    const float2* kf = Kf + (size_t)h * NFFT;
    const float invN = 1.0f / (float)NFFT;
    for (int i = tid; i < NFFT; i += NT) {
        float2 w = kf[i];
        float zr = re[i], zi = im[i];
        re[i] = (zr * w.x - zi * w.y) * invN;
        im[i] = (zr * w.y + zi * w.x) * invN;
    }

    fft_dit_inv(re, im, tid);

    float d = Dv[h];
    float* y0 = y + ((size_t)b0 * HCH + h) * LCONV;
    float* y1 = y + ((size_t)b1 * HCH + h) * LCONV;
#pragma unroll
    for (int j = 0; j < 16; ++j) {
        int i = tid + j * NT;
        y0[i] = re[i] + xr0[j] * d;
        y1[i] = im[i] + xr1[j] * d;
    }
}

extern "C" void kernel_launch(void* const* d_in, const int* in_sizes, int n_in,
                              void* d_out, int out_size, void* d_ws, size_t ws_size,
                              hipStream_t stream) {
    const float* x = (const float*)d_in[0];
    const float* k = (const float*)d_in[1];
    const float* Dv = (const float*)d_in[2];
    float* y = (float*)d_out;
    float2* Kf = (float2*)d_ws;  // needs HCH * NFFT * 8 = 64 MB

    kfft_kernel<<<HCH, NT, 0, stream>>>(k, Kf);
    conv_kernel<<<HCH * (BATCH / 2), NT, 0, stream>>>(x, Kf, Dv, y);
}

// Round 2
// 657.258 us; speedup vs baseline: 1.8755x; 1.8755x over previous
//
#include <hip/hip_runtime.h>

#define LCONV 4096
#define NFFT 8192
#define NT 256
#define HCH 1024
#define BATCH 16
#define PI_F 3.14159265358979f
#define C707 0.70710678118654752f
#define C16A 0.92387953251128674f   /* cos(pi/8) */
#define S16A 0.38268343236508977f   /* sin(pi/8) */

// XOR swizzle on complex index: kills LDS bank conflicts for all stage strides.
#define SW(i) ((i) ^ (((i) >> 4) & 15))

__device__ __forceinline__ float2 cadd(float2 a, float2 b){ return make_float2(a.x+b.x, a.y+b.y); }
__device__ __forceinline__ float2 csub(float2 a, float2 b){ return make_float2(a.x-b.x, a.y-b.y); }
__device__ __forceinline__ float2 cmul(float2 a, float2 b){ return make_float2(a.x*b.x - a.y*b.y, a.x*b.y + a.y*b.x); }
// multiply by e^{-i pi/4}, -i, e^{-3i pi/4} and conjugates
__device__ __forceinline__ float2 mW81 (float2 d){ return make_float2( C707*(d.x+d.y),  C707*(d.y-d.x)); }
__device__ __forceinline__ float2 mNI  (float2 d){ return make_float2( d.y, -d.x); }
__device__ __forceinline__ float2 mW83 (float2 d){ return make_float2( C707*(d.y-d.x), -C707*(d.x+d.y)); }
__device__ __forceinline__ float2 mW81c(float2 d){ return make_float2( C707*(d.x-d.y),  C707*(d.x+d.y)); }
__device__ __forceinline__ float2 mPI  (float2 d){ return make_float2(-d.y,  d.x); }
__device__ __forceinline__ float2 mW83c(float2 d){ return make_float2(-C707*(d.x+d.y),  C707*(d.x-d.y)); }

// DIF-8 network, natural inputs a[0..7]; output slot s holds b_{rev3[s]}, rev3={0,4,2,6,1,5,3,7}
__device__ __forceinline__ void net8_fwd(float2 a[8]) {
    float2 t0=cadd(a[0],a[4]), t4=csub(a[0],a[4]);
    float2 t1=cadd(a[1],a[5]), t5=mW81(csub(a[1],a[5]));
    float2 t2=cadd(a[2],a[6]), t6=mNI (csub(a[2],a[6]));
    float2 t3=cadd(a[3],a[7]), t7=mW83(csub(a[3],a[7]));
    float2 u0=cadd(t0,t2), u2=csub(t0,t2);
    float2 u1=cadd(t1,t3), u3=mNI(csub(t1,t3));
    float2 u4=cadd(t4,t6), u6=csub(t4,t6);
    float2 u5=cadd(t5,t7), u7=mNI(csub(t5,t7));
    a[0]=cadd(u0,u1); a[1]=csub(u0,u1);
    a[2]=cadd(u2,u3); a[3]=csub(u2,u3);
    a[4]=cadd(u4,u5); a[5]=csub(u4,u5);
    a[6]=cadd(u6,u7); a[7]=csub(u6,u7);
}
// conjugate network (computes B_k = sum c_n w^{+nk}), same slot mapping
__device__ __forceinline__ void net8_inv(float2 a[8]) {
    float2 t0=cadd(a[0],a[4]), t4=csub(a[0],a[4]);
    float2 t1=cadd(a[1],a[5]), t5=mW81c(csub(a[1],a[5]));
    float2 t2=cadd(a[2],a[6]), t6=mPI  (csub(a[2],a[6]));
    float2 t3=cadd(a[3],a[7]), t7=mW83c(csub(a[3],a[7]));
    float2 u0=cadd(t0,t2), u2=csub(t0,t2);
    float2 u1=cadd(t1,t3), u3=mPI(csub(t1,t3));
    float2 u4=cadd(t4,t6), u6=csub(t4,t6);
    float2 u5=cadd(t5,t7), u7=mPI(csub(t5,t7));
    a[0]=cadd(u0,u1); a[1]=csub(u0,u1);
    a[2]=cadd(u2,u3); a[3]=csub(u2,u3);
    a[4]=cadd(u4,u5); a[5]=csub(u4,u5);
    a[6]=cadd(u6,u7); a[7]=csub(u6,u7);
}

template<int M, bool INV>
__device__ __forceinline__ void bf8(float2* z, int idx, const float2 w[8]) {
    float2 a[8];
    if (!INV) {
#pragma unroll
        for (int q = 0; q < 8; ++q) a[q] = z[SW(idx + q*M)];
        net8_fwd(a);
        z[SW(idx      )] = a[0];
        z[SW(idx + 4*M)] = cmul(a[1], w[4]);
        z[SW(idx + 2*M)] = cmul(a[2], w[2]);
        z[SW(idx + 6*M)] = cmul(a[3], w[6]);
        z[SW(idx + 1*M)] = cmul(a[4], w[1]);
        z[SW(idx + 5*M)] = cmul(a[5], w[5]);
        z[SW(idx + 3*M)] = cmul(a[6], w[3]);
        z[SW(idx + 7*M)] = cmul(a[7], w[7]);
    } else {
        a[0] = z[SW(idx)];
#pragma unroll
        for (int q = 1; q < 8; ++q) a[q] = cmul(z[SW(idx + q*M)], w[q]);
        net8_inv(a);
        z[SW(idx      )] = a[0];
        z[SW(idx + 4*M)] = a[1];
        z[SW(idx + 2*M)] = a[2];
        z[SW(idx + 6*M)] = a[3];
        z[SW(idx + 1*M)] = a[4];
        z[SW(idx + 5*M)] = a[5];
        z[SW(idx + 3*M)] = a[6];
        z[SW(idx + 7*M)] = a[7];
    }
}

// Radix-8 stage at sub-size M. Twiddles: output q scaled by e^{∓2πi q j/(8M)}.
template<int M, bool INV>
__device__ __forceinline__ void stage8(float2* z, int tid) {
    __syncthreads();
    const float ang = (INV ? 2.0f : -2.0f) * PI_F / (8.0f * (float)M);
    if (M == 1024) {
        float2 w1, wstep;
        __sincosf(ang * (float)tid, &w1.y, &w1.x);
        __sincosf(ang * 256.0f, &wstep.y, &wstep.x);
#pragma unroll
        for (int s = 0; s < 4; ++s) {
            float2 w[8];
            w[0] = make_float2(1.f, 0.f);
            w[1] = w1;
#pragma unroll
            for (int q = 2; q < 8; ++q) w[q] = cmul(w[q-1], w1);
            bf8<M, INV>(z, tid + 256*s, w);
            w1 = cmul(w1, wstep);
        }
    } else {
        const int LOG2M = (M == 128) ? 7 : 4;
        int j  = tid & (M - 1);
        int g0 = tid >> LOG2M;
        float2 w[8];
        w[0] = make_float2(1.f, 0.f);
        __sincosf(ang * (float)j, &w[1].y, &w[1].x);
#pragma unroll
        for (int q = 2; q < 8; ++q) w[q] = cmul(w[q-1], w[1]);
#pragma unroll
        for (int s = 0; s < 4; ++s) {
            int base = (g0 + (256 / M) * s) * (8 * M);
            bf8<M, INV>(z, base + j, w);
        }
    }
}

// Final radix-16 on contiguous 16-chunks (twiddle-free externally; W16 constants internal).
// Output within chunk is in NATURAL spectral order.
template<bool INV>
__device__ __forceinline__ void stage16(float2* z, int tid) {
    __syncthreads();
#pragma unroll
    for (int s = 0; s < 2; ++s) {
        int b = (tid + 256*s) * 16;
        float2 a[16];
#pragma unroll
        for (int e = 0; e < 16; ++e) a[e] = z[SW(b + e)];
        float2 lo[8], hi[8];
#pragma unroll
        for (int i = 0; i < 8; ++i) {
            lo[i] = cadd(a[i], a[i+8]);
            hi[i] = csub(a[i], a[i+8]);
        }
        if (!INV) {
            hi[1] = cmul(hi[1], make_float2( C16A, -S16A));
            hi[2] = mW81(hi[2]);
            hi[3] = cmul(hi[3], make_float2( S16A, -C16A));
            hi[4] = mNI (hi[4]);
            hi[5] = cmul(hi[5], make_float2(-S16A, -C16A));
            hi[6] = mW83(hi[6]);
            hi[7] = cmul(hi[7], make_float2(-C16A, -S16A));
            net8_fwd(lo); net8_fwd(hi);
        } else {
            hi[1] = cmul(hi[1], make_float2( C16A,  S16A));
            hi[2] = mW81c(hi[2]);
            hi[3] = cmul(hi[3], make_float2( S16A,  C16A));
            hi[4] = mPI (hi[4]);
            hi[5] = cmul(hi[5], make_float2(-S16A,  C16A));
            hi[6] = mW83c(hi[6]);
            hi[7] = cmul(hi[7], make_float2(-C16A,  S16A));
            net8_inv(lo); net8_inv(hi);
        }
        const int rev3[8] = {0,4,2,6,1,5,3,7};
#pragma unroll
        for (int s2 = 0; s2 < 8; ++s2) {
            z[SW(b + 2*rev3[s2]    )] = lo[s2];
            z[SW(b + 2*rev3[s2] + 1)] = hi[s2];
        }
    }
}

__global__ __launch_bounds__(NT) void kfft_kernel(const float* __restrict__ k,
                                                  float2* __restrict__ Kf) {
    __shared__ float2 z[NFFT];
    int h = blockIdx.x, tid = threadIdx.x;
    const float* kr = k + (size_t)h * LCONV;
#pragma unroll
    for (int jj = 0; jj < 16; ++jj) {
        int i = tid + NT*jj;
        z[SW(i)]         = make_float2(kr[i], 0.f);
        z[SW(i + LCONV)] = make_float2(0.f, 0.f);
    }
    stage8<1024, false>(z, tid);
    stage8<128,  false>(z, tid);
    stage8<16,   false>(z, tid);
    stage16<false>(z, tid);
    __syncthreads();
    const float invN = 1.0f / (float)NFFT;   // fold 1/N into Kf
    float2* out = Kf + (size_t)h * NFFT;
#pragma unroll
    for (int jj = 0; jj < 32; ++jj) {
        int i = tid + NT*jj;
        float2 v = z[SW(i)];
        out[i] = make_float2(v.x * invN, v.y * invN);
    }
}

__global__ __launch_bounds__(NT) void conv_kernel(const float* __restrict__ x,
                                                  const float2* __restrict__ Kf,
                                                  const float* __restrict__ Dv,
                                                  float* __restrict__ y) {
    __shared__ float2 z[NFFT];
    int bid = blockIdx.x;
    int h = bid >> 3;          // 8 consecutive blocks share one h (L2/L3 reuse of Kf)
    int pb = bid & 7;
    int b0 = pb*2, b1 = pb*2 + 1;
    int tid = threadIdx.x;

    const float* x0 = x + ((size_t)b0 * HCH + h) * LCONV;
    const float* x1 = x + ((size_t)b1 * HCH + h) * LCONV;

    float2 xr[16];
#pragma unroll
    for (int jj = 0; jj < 16; ++jj) {
        int i = tid + NT*jj;
        xr[jj] = make_float2(x0[i], x1[i]);
        z[SW(i)]         = xr[jj];
        z[SW(i + LCONV)] = make_float2(0.f, 0.f);
    }

    stage8<1024, false>(z, tid);
    stage8<128,  false>(z, tid);
    stage8<16,   false>(z, tid);
    stage16<false>(z, tid);

    __syncthreads();
    const float2* kf = Kf + (size_t)h * NFFT;
#pragma unroll
    for (int jj = 0; jj < 32; ++jj) {
        int i = tid + NT*jj;
        z[SW(i)] = cmul(z[SW(i)], kf[i]);
    }

    stage16<true>(z, tid);
    stage8<16,   true>(z, tid);
    stage8<128,  true>(z, tid);
    stage8<1024, true>(z, tid);

    __syncthreads();
    float d = Dv[h];
    float* y0 = y + ((size_t)b0 * HCH + h) * LCONV;
    float* y1 = y + ((size_t)b1 * HCH + h) * LCONV;
#pragma unroll
    for (int jj = 0; jj < 16; ++jj) {
        int i = tid + NT*jj;
        float2 r = z[SW(i)];
        y0[i] = r.x + xr[jj].x * d;
        y1[i] = r.y + xr[jj].y * d;
    }
}

extern "C" void kernel_launch(void* const* d_in, const int* in_sizes, int n_in,
                              void* d_out, int out_size, void* d_ws, size_t ws_size,
                              hipStream_t stream) {
    const float* x  = (const float*)d_in[0];
    const float* k  = (const float*)d_in[1];
    const float* Dv = (const float*)d_in[2];
    float* y  = (float*)d_out;
    float2* Kf = (float2*)d_ws;   // HCH * NFFT * 8 B = 64 MB

    kfft_kernel<<<HCH, NT, 0, stream>>>(k, Kf);
    conv_kernel<<<HCH * (BATCH/2), NT, 0, stream>>>(x, Kf, Dv, y);
}